// Round 1
// baseline (93.446 us; speedup 1.0000x reference)
//
#include <hip/hip_runtime.h>
#include <hip/hip_bf16.h>

// Problem constants (match reference)
#define PB 8
#define PS 2048
#define PN 4096
#define PD 256
// MAX_W = 16 (loop bound comes from width, <= 15)

// One wave (64 lanes) per span. lane i holds float4 = elements [4i, 4i+4) of D=256.
// Block = 256 threads = 4 spans. Grid = B*N/4 = 8192 blocks.
__global__ __launch_bounds__(256) void span_mean_kernel(
    const float* __restrict__ seq,     // (B, S, D) f32
    const int*   __restrict__ spans,   // (B, N, 2) i32: start, end
    float*       __restrict__ out)     // (B, N, D) f32
{
    const int span = (blockIdx.x << 2) | (threadIdx.x >> 6);   // 0 .. B*N-1
    const int lane = threadIdx.x & 63;

    const int b = span >> 12;          // / N (N = 4096)

    // start/end for this span (wave-uniform: all 64 lanes read same int2,
    // broadcast from cache)
    const int2 se    = ((const int2*)spans)[span];
    const int  start = se.x;
    const int  width = se.y - se.x;    // count = width + 1, in [1, 16]

    const float inv = 1.0f / (float)(width + 1);

    // Base of row `start` for this batch, offset to this lane's float4.
    const float* base = seq + (((size_t)b * PS + (size_t)start) * PD) + (lane << 2);

    float4 acc = make_float4(0.f, 0.f, 0.f, 0.f);
    // width is wave-uniform -> no divergence; rows are contiguous (start..end)
    for (int w = 0; w <= width; ++w) {
        const float4 v = *(const float4*)(base + (size_t)w * PD);
        acc.x += v.x; acc.y += v.y; acc.z += v.z; acc.w += v.w;
    }
    acc.x *= inv; acc.y *= inv; acc.z *= inv; acc.w *= inv;

    *(float4*)(out + (size_t)span * PD + (lane << 2)) = acc;
}

extern "C" void kernel_launch(void* const* d_in, const int* in_sizes, int n_in,
                              void* d_out, int out_size, void* d_ws, size_t ws_size,
                              hipStream_t stream) {
    const float* seq   = (const float*)d_in[0];   // (B,S,D) f32
    const int*   spans = (const int*)d_in[1];     // (B,N,2) i32
    float*       out   = (float*)d_out;           // (B,N,D) f32

    const int n_spans = PB * PN;                  // 32768
    dim3 grid(n_spans / 4);                       // 4 spans per 256-thread block
    dim3 block(256);
    span_mean_kernel<<<grid, block, 0, stream>>>(seq, spans, out);
}

// Round 2
// 82.624 us; speedup vs baseline: 1.1310x; 1.1310x over previous
//
#include <hip/hip_runtime.h>
#include <hip/hip_bf16.h>

// Problem constants (match reference)
#define PB 8          // batches
#define PS 2048       // sequence length
#define PN 4096       // spans per batch
#define PD 256        // feature dim
// MAX_W = 16 -> width in [0,15], count = width+1 in [1,16]

// One wave (64 lanes) per span; lane i owns float4 [4i,4i+4) of D=256.
// Block = 256 threads = 4 spans. Grid = 8192 blocks.
//
// XCD-aware swizzle: blocks are dispatched round-robin across the 8 XCDs,
// so we map batch = blockIdx % 8. Each XCD then gathers from a single
// batch's 2 MiB slice of seq -> fits its 4 MiB L2 (vs 16 MiB unswizzled).
__global__ __launch_bounds__(256) void span_mean_kernel(
    const float* __restrict__ seq,     // (B, S, D) f32
    const int*   __restrict__ spans,   // (B, N, 2) i32: start, end
    float*       __restrict__ out)     // (B, N, D) f32
{
    const int b       = blockIdx.x & 7;          // batch == XCD (round-robin)
    const int blk     = blockIdx.x >> 3;         // 0..1023 within batch
    const int span_ib = (blk << 2) | (threadIdx.x >> 6);   // 0..4095 in batch
    const int span    = (b << 12) | span_ib;     // global span id
    const int lane    = threadIdx.x & 63;

    // start/end for this span (wave-uniform broadcast)
    const int2 se    = ((const int2*)spans)[span];
    const int  start = se.x;
    const int  width = se.y - se.x;              // 0..15

    const float inv = 1.0f / (float)(width + 1);

    const float* base = seq + (((size_t)b * PS + (size_t)start) * PD) + (lane << 2);

    // Unroll by 2: two independent loads in flight per iteration.
    float4 acc0 = make_float4(0.f, 0.f, 0.f, 0.f);
    float4 acc1 = make_float4(0.f, 0.f, 0.f, 0.f);
    int w = 0;
    for (; w + 1 <= width; w += 2) {
        const float4 v0 = *(const float4*)(base + (size_t)w       * PD);
        const float4 v1 = *(const float4*)(base + (size_t)(w + 1) * PD);
        acc0.x += v0.x; acc0.y += v0.y; acc0.z += v0.z; acc0.w += v0.w;
        acc1.x += v1.x; acc1.y += v1.y; acc1.z += v1.z; acc1.w += v1.w;
    }
    if (w <= width) {
        const float4 v = *(const float4*)(base + (size_t)w * PD);
        acc0.x += v.x; acc0.y += v.y; acc0.z += v.z; acc0.w += v.w;
    }
    acc0.x = (acc0.x + acc1.x) * inv;
    acc0.y = (acc0.y + acc1.y) * inv;
    acc0.z = (acc0.z + acc1.z) * inv;
    acc0.w = (acc0.w + acc1.w) * inv;

    *(float4*)(out + (size_t)span * PD + (lane << 2)) = acc0;
}

extern "C" void kernel_launch(void* const* d_in, const int* in_sizes, int n_in,
                              void* d_out, int out_size, void* d_ws, size_t ws_size,
                              hipStream_t stream) {
    const float* seq   = (const float*)d_in[0];   // (B,S,D) f32
    const int*   spans = (const int*)d_in[1];     // (B,N,2) i32
    float*       out   = (float*)d_out;           // (B,N,D) f32

    const int n_spans = PB * PN;                  // 32768
    dim3 grid(n_spans / 4);                       // 8192 blocks, 4 spans each
    dim3 block(256);
    span_mean_kernel<<<grid, block, 0, stream>>>(seq, spans, out);
}